// Round 4
// baseline (165.420 us; speedup 1.0000x reference)
//
#include <hip/hip_runtime.h>
#include <math.h>

// Problem constants: B=32, F=2048, hw=49, A=1.
#define BB    32
#define FF    2048
#define HW    49
#define ROWS  (BB * FF)
#define DPAD  64
#define SPLIT 4
#define GSTEP 64
#define FTG   4                          // f sub-tiles per block (ft-loop)
#define GHALF (FF / SPLIT)               // 512
#define NSTEP (GHALF / GSTEP)            // 8

typedef float f32x16 __attribute__((ext_vector_type(16)));
typedef short bf16x8 __attribute__((ext_vector_type(8)));

// fp32 -> bf16 hi + bf16 lo (both RNE), packed (hi<<16)|lo.
__device__ inline unsigned bf16pack(float v) {
    unsigned u = __float_as_uint(v);
    unsigned hi = (u + 0x7FFFu + ((u >> 16) & 1u)) >> 16;
    float hf = __uint_as_float(hi << 16);
    float lof = v - hf;
    unsigned ul = __float_as_uint(lof);
    unsigned lo = (ul + 0x7FFFu + ((ul >> 16) & 1u)) >> 16;
    return (hi << 16) | lo;
}

__device__ inline void unpack8(uint4 a, uint4 b, bf16x8& h, bf16x8& l) {
    unsigned w[8] = {a.x, a.y, a.z, a.w, b.x, b.y, b.z, b.w};
    #pragma unroll
    for (int i = 0; i < 8; ++i) {
        h[i] = (short)(w[i] >> 16);
        l[i] = (short)(w[i] & 0xFFFFu);
    }
}

// ---------------------------------------------------------------------------
// prep: M[j,d] = sum_e Wq[e,j] Wk[e,d] / 7  -> Mtpk[d][j] (hi/lo packed)
//       u[d]   = sum_e Wv[e,d] * Wout[e]
// ---------------------------------------------------------------------------
__global__ __launch_bounds__(256) void prep_kernel(
    const float* __restrict__ Wqkv, const float* __restrict__ Wout,
    unsigned* __restrict__ Mtpk, float* __restrict__ u)
{
    __shared__ float W2[98][52];
    const int tid = threadIdx.x;
    if (blockIdx.x < 16) {
        for (int i = tid; i < 98 * 52; i += 256) {
            int e = i / 52, j = i - e * 52;
            W2[e][j] = (j < HW) ? Wqkv[e * HW + j] : 0.f;
        }
        __syncthreads();
        const int d = blockIdx.x * 4 + (tid >> 6);
        const int j = tid & 63;
        float s = 0.f;
        if (d < HW && j < HW) {
            for (int e = 0; e < HW; ++e) s = fmaf(W2[e][j], W2[49 + e][d], s);
            s *= (1.f / 7.f);
        }
        Mtpk[d * 64 + j] = bf16pack(s);
    } else {
        if (tid < 64) {
            float s = 0.f;
            if (tid < HW)
                for (int e = 0; e < HW; ++e)
                    s = fmaf(Wqkv[(98 + e) * HW + tid], Wout[e], s);
            u[tid] = s;
        }
    }
}

// ---------------------------------------------------------------------------
// xymm (fused xconv+ymm): per 128 rows: load x fp32, build bf16 hi/lo frags
// in-register, write xh/xl panels, w = x.u, and y = x.M via 3-MFMA hi/lo,
// writing packed u32 panel ypk[row][64].
// ---------------------------------------------------------------------------
__global__ __launch_bounds__(256) void xymm_kernel(
    const float* __restrict__ x, const unsigned* __restrict__ Mtpk,
    const float* __restrict__ u,
    unsigned short* __restrict__ xh, unsigned short* __restrict__ xl,
    unsigned* __restrict__ ypk, float* __restrict__ wv)
{
    __shared__ float ush[64];
    const int tid = threadIdx.x, lane = tid & 63, wid = tid >> 6;
    const int col = lane & 31, half = lane >> 5;
    if (tid < 64) ush[tid] = u[tid];

    // Mt B-fragments (hi/lo), as in the verified ymm kernel
    bf16x8 mh[2][4], ml[2][4];
    #pragma unroll
    for (int dt = 0; dt < 2; ++dt)
        #pragma unroll
        for (int ks = 0; ks < 4; ++ks) {
            const unsigned* mp = Mtpk + (dt * 32 + col) * 64 + ks * 16 + half * 8;
            unpack8(*(const uint4*)mp, *(const uint4*)(mp + 4), mh[dt][ks], ml[dt][ks]);
        }
    __syncthreads();

    const int row = blockIdx.x * 128 + wid * 32 + col;
    const float* xp = x + (size_t)row * HW;

    // this lane's half of the row -> A-frags + panel writes + w partial
    bf16x8 ah[4], al[4];
    float wp = 0.f;
    #pragma unroll
    for (int ks = 0; ks < 4; ++ks) {
        #pragma unroll
        for (int i = 0; i < 8; ++i) {
            int d = ks * 16 + half * 8 + i;
            float t = (d < HW) ? xp[d] : 0.f;
            wp = fmaf(t, ush[d], wp);
            unsigned p = bf16pack(t);
            ah[ks][i] = (short)(p >> 16);
            al[ks][i] = (short)(p & 0xFFFFu);
        }
        const size_t o = (size_t)row * DPAD + ks * 16 + half * 8;
        *(bf16x8*)(xh + o) = ah[ks];
        *(bf16x8*)(xl + o) = al[ks];
    }
    wp += __shfl_xor(wp, 32);
    if (half == 0) wv[row] = wp;

    f32x16 acc[2];
    #pragma unroll
    for (int i = 0; i < 16; ++i) { acc[0][i] = 0.f; acc[1][i] = 0.f; }

    #pragma unroll
    for (int ks = 0; ks < 4; ++ks)
        #pragma unroll
        for (int dt = 0; dt < 2; ++dt) {
            acc[dt] = __builtin_amdgcn_mfma_f32_32x32x16_bf16(ah[ks], ml[dt][ks], acc[dt], 0, 0, 0);
            acc[dt] = __builtin_amdgcn_mfma_f32_32x32x16_bf16(al[ks], mh[dt][ks], acc[dt], 0, 0, 0);
            acc[dt] = __builtin_amdgcn_mfma_f32_32x32x16_bf16(ah[ks], mh[dt][ks], acc[dt], 0, 0, 0);
        }

    const int r0 = blockIdx.x * 128 + wid * 32;
    #pragma unroll
    for (int dt = 0; dt < 2; ++dt)
        #pragma unroll
        for (int reg = 0; reg < 16; ++reg) {
            int drow = (reg & 3) + 8 * (reg >> 2) + 4 * half;
            ypk[(size_t)(r0 + drow) * DPAD + dt * 32 + col] = bf16pack(acc[dt][reg]);
        }
}

// ---------------------------------------------------------------------------
// attn: scores = y . x^T (3-MFMA hi/lo), no-max softmax, scalar value w.
// Block covers 512 f-cols (4 waves x 4 ft-subtiles) x 512 g-rows (sp split).
// K-tile = 64 g-rows staged per step (reg-staged, 16-slot XOR swizzle).
// ---------------------------------------------------------------------------
__global__ __launch_bounds__(256, 2) void attn_kernel(
    const unsigned short* __restrict__ xh, const unsigned short* __restrict__ xl,
    const unsigned* __restrict__ ypk, const float* __restrict__ wv,
    float* __restrict__ partL, float* __restrict__ partA)
{
    __shared__ __align__(16) unsigned char Kt[2][GSTEP * 256];   // 2 x 16 KB
    __shared__ __align__(16) float wssh[GHALF];                  // 2 KB

    // XCD-chunked swizzle: 512 blocks, 64 logical ids per XCD -> 4 b's/XCD.
    const int bid = blockIdx.x;
    const int L = (bid & 7) * 64 + (bid >> 3);
    const int b   = L >> 4;
    const int ftg = (L >> 2) & 3;
    const int sp  = L & 3;

    const int tid  = threadIdx.x;
    const int lane = tid & 63;
    const int wid  = tid >> 6;
    const int col  = lane & 31;
    const int half = lane >> 5;
    const int fblk0  = ftg * 512 + wid * 128;
    const int gstart = sp * GHALF;
    const size_t bq = (size_t)b * FF;

    // hoist y fragments for 4 f-subtiles (B operand), unpack hi/lo
    bf16x8 qhf[FTG][4], qlf[FTG][4];
    #pragma unroll
    for (int fs = 0; fs < FTG; ++fs)
        #pragma unroll
        for (int ks = 0; ks < 4; ++ks) {
            const unsigned* yp =
                ypk + (bq + fblk0 + fs * 32 + col) * DPAD + ks * 16 + half * 8;
            unpack8(*(const uint4*)yp, *(const uint4*)(yp + 4),
                    qhf[fs][ks], qlf[fs][ks]);
        }

    for (int i = tid; i < GHALF; i += 256) wssh[i] = wv[bq + gstart + i];

    // staging: thread t -> row = t>>2 (0..63), quarter k4 = t&3 covering
    // chunks c = k4*4..k4*4+3 (64 contiguous bytes in xh or xl).
    const int row_s = tid >> 2;
    const int k4 = tid & 3;
    const int r15s = row_s & 15;
    const unsigned short* sbase = (k4 < 2) ? xh : xl;
    const int soff = (k4 & 1) * 32;                  // shorts
    int slot[4];
    #pragma unroll
    for (int i = 0; i < 4; ++i) slot[i] = ((k4 * 4 + i) ^ r15s) << 4;
    const int wrow = row_s << 8;

    uint4 st[4];
    {
        const unsigned short* sp0 = sbase + (bq + gstart + row_s) * DPAD + soff;
        #pragma unroll
        for (int i = 0; i < 4; ++i) st[i] = *(const uint4*)(sp0 + i * 8);
    }

    float lsum[FTG], asum[FTG];
    #pragma unroll
    for (int fs = 0; fs < FTG; ++fs) { lsum[fs] = 0.f; asum[fs] = 0.f; }

    for (int t = 0; t < NSTEP; ++t) {
        const int buf = t & 1;
        #pragma unroll
        for (int i = 0; i < 4; ++i)
            *(uint4*)(&Kt[buf][wrow + slot[i]]) = st[i];
        if (t + 1 < NSTEP) {
            const unsigned short* sp1 =
                sbase + (bq + gstart + (t + 1) * GSTEP + row_s) * DPAD + soff;
            #pragma unroll
            for (int i = 0; i < 4; ++i) st[i] = *(const uint4*)(sp1 + i * 8);
        }
        __syncthreads();

        #pragma unroll
        for (int gsub = 0; gsub < 2; ++gsub) {
            const int arow = gsub * 32 + col;
            const int rbase = arow << 8;
            const int ar15 = arow & 15;
            bf16x8 ahf[4], alf[4];
            #pragma unroll
            for (int ks = 0; ks < 4; ++ks) {
                const int ch = ks * 2 + half;
                ahf[ks] = *(const bf16x8*)(&Kt[buf][rbase + ((ch ^ ar15) << 4)]);
                alf[ks] = *(const bf16x8*)(&Kt[buf][rbase + (((8 + ch) ^ ar15) << 4)]);
            }
            const float* wpb = wssh + t * GSTEP + gsub * 32 + 4 * half;
            #pragma unroll
            for (int fs = 0; fs < FTG; ++fs) {
                f32x16 acc;
                #pragma unroll
                for (int i = 0; i < 16; ++i) acc[i] = 0.f;
                #pragma unroll
                for (int ks = 0; ks < 4; ++ks) {
                    acc = __builtin_amdgcn_mfma_f32_32x32x16_bf16(ahf[ks], qlf[fs][ks], acc, 0, 0, 0);
                    acc = __builtin_amdgcn_mfma_f32_32x32x16_bf16(alf[ks], qhf[fs][ks], acc, 0, 0, 0);
                    acc = __builtin_amdgcn_mfma_f32_32x32x16_bf16(ahf[ks], qhf[fs][ks], acc, 0, 0, 0);
                }
                // D row g = (reg&3) + 8*(reg>>2) + 4*half
                #pragma unroll
                for (int q = 0; q < 4; ++q) {
                    float4 w4 = *(const float4*)(wpb + q * 8);
                    float p0 = __expf(acc[q * 4 + 0]);
                    float p1 = __expf(acc[q * 4 + 1]);
                    float p2 = __expf(acc[q * 4 + 2]);
                    float p3 = __expf(acc[q * 4 + 3]);
                    lsum[fs] += ((p0 + p1) + (p2 + p3));
                    asum[fs] = fmaf(p0, w4.x, fmaf(p1, w4.y,
                               fmaf(p2, w4.z, fmaf(p3, w4.w, asum[fs]))));
                }
            }
        }
    }

    #pragma unroll
    for (int fs = 0; fs < FTG; ++fs) {
        float l = lsum[fs] + __shfl_xor(lsum[fs], 32);
        float a = asum[fs] + __shfl_xor(asum[fs], 32);
        if (half == 0) {
            size_t o = ((size_t)sp * BB + b) * FF + fblk0 + fs * 32 + col;
            partL[o] = l;
            partA[o] = a;
        }
    }
}

// ---------------------------------------------------------------------------
// bn: combine split partials, BatchNorm over batch per channel f.
// ---------------------------------------------------------------------------
__global__ __launch_bounds__(256) void bn_kernel(
    const float* __restrict__ partL, const float* __restrict__ partA,
    const float* __restrict__ gamma, const float* __restrict__ beta,
    float* __restrict__ out)
{
    const int f = blockIdx.x * 256 + threadIdx.x;
    float v[BB];
    float mean = 0.f;
    #pragma unroll
    for (int b = 0; b < BB; ++b) {
        float l = 0.f, a = 0.f;
        #pragma unroll
        for (int s = 0; s < SPLIT; ++s) {
            l += partL[((size_t)s * BB + b) * FF + f];
            a += partA[((size_t)s * BB + b) * FF + f];
        }
        v[b] = a / l;
        mean += v[b];
    }
    mean *= (1.f / BB);
    float var = 0.f;
    #pragma unroll
    for (int b = 0; b < BB; ++b) {
        float d = v[b] - mean;
        var = fmaf(d, d, var);
    }
    var *= (1.f / BB);
    const float inv = rsqrtf(var + 1e-5f);
    const float g = gamma[f], be = beta[f];
    #pragma unroll
    for (int b = 0; b < BB; ++b)
        out[((size_t)b << 11) + f] = (v[b] - mean) * inv * g + be;
}

// ---------------------------------------------------------------------------
extern "C" void kernel_launch(void* const* d_in, const int* in_sizes, int n_in,
                              void* d_out, int out_size, void* d_ws, size_t ws_size,
                              hipStream_t stream)
{
    const float* x     = (const float*)d_in[0];
    const float* Wqkv  = (const float*)d_in[1];
    const float* Wout  = (const float*)d_in[2];
    // d_in[3] = b_out: cancels exactly under BatchNorm mean subtraction.
    const float* gamma = (const float*)d_in[4];
    const float* beta  = (const float*)d_in[5];

    char* wsb = (char*)d_ws;
    const size_t PANEL = (size_t)ROWS * DPAD * sizeof(unsigned short);  // 8 MB
    unsigned short* xh = (unsigned short*)(wsb);
    unsigned short* xl = (unsigned short*)(wsb + PANEL);
    unsigned*      ypk = (unsigned*)(wsb + 2 * PANEL);                  // 16 MB
    float*          wv = (float*)(wsb + 4 * PANEL);                     // 256 KB
    unsigned*     Mtpk = (unsigned*)(wsb + 4 * PANEL + 262144);         // 16 KB
    float*           u = (float*)(wsb + 4 * PANEL + 262144 + 16384);
    float*       partL = (float*)(wsb + 4 * PANEL + 262144 + 17408);
    float*       partA = partL + (size_t)SPLIT * BB * FF;

    prep_kernel<<<dim3(17), dim3(256), 0, stream>>>(Wqkv, Wout, Mtpk, u);

    xymm_kernel<<<dim3(ROWS / 128), dim3(256), 0, stream>>>(
        x, Mtpk, u, xh, xl, ypk, wv);

    attn_kernel<<<dim3(BB * FTG * SPLIT), dim3(256), 0, stream>>>(
        xh, xl, ypk, wv, partL, partA);

    bn_kernel<<<dim3(FF / 256), dim3(256), 0, stream>>>(
        partL, partA, gamma, beta, (float*)d_out);
}

// Round 5
// 138.329 us; speedup vs baseline: 1.1958x; 1.1958x over previous
//
#include <hip/hip_runtime.h>
#include <math.h>

// Problem constants: B=32, F=2048, hw=49, A=1.
#define BB    32
#define FF    2048
#define HW    49
#define ROWS  (BB * FF)
#define DPAD  64
#define SPLIT 8
#define GSTEP 64
#define FTG   2                          // f sub-tiles per wave
#define GHALF (FF / SPLIT)               // 256
#define NSTEP (GHALF / GSTEP)            // 4

typedef float f32x16 __attribute__((ext_vector_type(16)));
typedef _Float16 f16x8 __attribute__((ext_vector_type(8)));
typedef short s16x8 __attribute__((ext_vector_type(8)));

// fp32 -> fp16 hi + fp16 lo (RNE), packed (hi<<16)|lo. Combined rel err ~2^-22.
__device__ inline unsigned f16pack(float v) {
    _Float16 h = (_Float16)v;
    _Float16 l = (_Float16)(v - (float)h);
    unsigned hb = (unsigned)__builtin_bit_cast(unsigned short, h);
    unsigned lb = (unsigned)__builtin_bit_cast(unsigned short, l);
    return (hb << 16) | lb;
}

__device__ inline void unpack8(uint4 a, uint4 b, f16x8& h, f16x8& l) {
    unsigned w[8] = {a.x, a.y, a.z, a.w, b.x, b.y, b.z, b.w};
    s16x8 hs, ls;
    #pragma unroll
    for (int i = 0; i < 8; ++i) {
        hs[i] = (short)(w[i] >> 16);
        ls[i] = (short)(w[i] & 0xFFFFu);
    }
    h = __builtin_bit_cast(f16x8, hs);
    l = __builtin_bit_cast(f16x8, ls);
}

// ---------------------------------------------------------------------------
// prep: M[j,d] = sum_e Wq[e,j] Wk[e,d] / 7  -> Mtpk[d][j] (fp16 hi/lo packed)
//       u[d]   = sum_e Wv[e,d] * Wout[e]
// ---------------------------------------------------------------------------
__global__ __launch_bounds__(256) void prep_kernel(
    const float* __restrict__ Wqkv, const float* __restrict__ Wout,
    unsigned* __restrict__ Mtpk, float* __restrict__ u)
{
    __shared__ float W2[98][52];
    const int tid = threadIdx.x;
    if (blockIdx.x < 16) {
        for (int i = tid; i < 98 * 52; i += 256) {
            int e = i / 52, j = i - e * 52;
            W2[e][j] = (j < HW) ? Wqkv[e * HW + j] : 0.f;
        }
        __syncthreads();
        const int d = blockIdx.x * 4 + (tid >> 6);
        const int j = tid & 63;
        float s = 0.f;
        if (d < HW && j < HW) {
            for (int e = 0; e < HW; ++e) s = fmaf(W2[e][j], W2[49 + e][d], s);
            s *= (1.f / 7.f);
        }
        Mtpk[d * 64 + j] = f16pack(s);
    } else {
        if (tid < 64) {
            float s = 0.f;
            if (tid < HW)
                for (int e = 0; e < HW; ++e)
                    s = fmaf(Wqkv[(98 + e) * HW + tid], Wout[e], s);
            u[tid] = s;
        }
    }
}

// ---------------------------------------------------------------------------
// xymm: per 128 rows: coalesced x load via LDS bounce, fp16 hi/lo panels
// xh/xl, w = x.u, y = x.M (3-MFMA fp16 hi/lo) -> packed u32 panel ypk.
// ---------------------------------------------------------------------------
__global__ __launch_bounds__(256) void xymm_kernel(
    const float* __restrict__ x, const unsigned* __restrict__ Mtpk,
    const float* __restrict__ u,
    unsigned short* __restrict__ xh, unsigned short* __restrict__ xl,
    unsigned* __restrict__ ypk, float* __restrict__ wv)
{
    __shared__ float xsh[128 * HW];
    __shared__ float ush[64];
    const int tid = threadIdx.x, lane = tid & 63, wid = tid >> 6;
    const int col = lane & 31, half = lane >> 5;
    if (tid < 64) ush[tid] = u[tid];

    // coalesced x load: 128 rows x 49 floats contiguous
    {
        const float* xb = x + (size_t)blockIdx.x * 128 * HW;
        for (int i = tid; i < 128 * HW; i += 256) xsh[i] = xb[i];
    }

    // Mt B-fragments (hi/lo)
    f16x8 mh[2][4], ml[2][4];
    #pragma unroll
    for (int dt = 0; dt < 2; ++dt)
        #pragma unroll
        for (int ks = 0; ks < 4; ++ks) {
            const unsigned* mp = Mtpk + (dt * 32 + col) * 64 + ks * 16 + half * 8;
            unpack8(*(const uint4*)mp, *(const uint4*)(mp + 4), mh[dt][ks], ml[dt][ks]);
        }
    __syncthreads();

    const int rloc = wid * 32 + col;
    const int row = blockIdx.x * 128 + rloc;

    f16x8 ah[4], al[4];
    float wp = 0.f;
    #pragma unroll
    for (int ks = 0; ks < 4; ++ks) {
        s16x8 hs, ls;
        #pragma unroll
        for (int i = 0; i < 8; ++i) {
            int d = ks * 16 + half * 8 + i;
            float t = (d < HW) ? xsh[rloc * HW + d] : 0.f;
            wp = fmaf(t, ush[d], wp);
            _Float16 h = (_Float16)t;
            _Float16 l = (_Float16)(t - (float)h);
            hs[i] = __builtin_bit_cast(short, h);
            ls[i] = __builtin_bit_cast(short, l);
        }
        ah[ks] = __builtin_bit_cast(f16x8, hs);
        al[ks] = __builtin_bit_cast(f16x8, ls);
        const size_t o = (size_t)row * DPAD + ks * 16 + half * 8;
        *(f16x8*)(xh + o) = ah[ks];
        *(f16x8*)(xl + o) = al[ks];
    }
    wp += __shfl_xor(wp, 32);
    if (half == 0) wv[row] = wp;

    f32x16 acc[2];
    #pragma unroll
    for (int i = 0; i < 16; ++i) { acc[0][i] = 0.f; acc[1][i] = 0.f; }

    #pragma unroll
    for (int ks = 0; ks < 4; ++ks)
        #pragma unroll
        for (int dt = 0; dt < 2; ++dt) {
            acc[dt] = __builtin_amdgcn_mfma_f32_32x32x16_f16(ah[ks], ml[dt][ks], acc[dt], 0, 0, 0);
            acc[dt] = __builtin_amdgcn_mfma_f32_32x32x16_f16(al[ks], mh[dt][ks], acc[dt], 0, 0, 0);
            acc[dt] = __builtin_amdgcn_mfma_f32_32x32x16_f16(ah[ks], mh[dt][ks], acc[dt], 0, 0, 0);
        }

    const int r0 = blockIdx.x * 128 + wid * 32;
    #pragma unroll
    for (int dt = 0; dt < 2; ++dt)
        #pragma unroll
        for (int reg = 0; reg < 16; ++reg) {
            int drow = (reg & 3) + 8 * (reg >> 2) + 4 * half;
            ypk[(size_t)(r0 + drow) * DPAD + dt * 32 + col] = f16pack(acc[dt][reg]);
        }
}

// ---------------------------------------------------------------------------
// attn: scores = y . x^T (3-MFMA fp16 hi/lo), no-max softmax, scalar value w.
// Block: 4 waves x 64 f-cols (FTG=2) x GHALF=256 g-rows. K-tile 64 rows
// double-buffered; lane-contiguous LDS writes + inverse-swizzled source
// (conflict-free both sides). Each XCD sweeps its 4 b's sequentially ->
// ~1-2 MB live working set, L2-resident.
// ---------------------------------------------------------------------------
__global__ __launch_bounds__(256, 2) void attn_kernel(
    const unsigned short* __restrict__ xh, const unsigned short* __restrict__ xl,
    const unsigned* __restrict__ ypk, const float* __restrict__ wv,
    float* __restrict__ partL, float* __restrict__ partA)
{
    __shared__ __align__(16) unsigned char Kt[2][GSTEP * 256];   // 2 x 16 KB
    __shared__ __align__(16) float wssh[GHALF];                  // 1 KB

    // XCD-chunked swizzle: 2048 blocks, 256 logical per XCD -> 4 b's/XCD.
    const int bid = blockIdx.x;
    const int L = (bid & 7) * 256 + (bid >> 3);
    const int b   = L >> 6;
    const int r63 = L & 63;
    const int ftg = r63 >> 3;       // 0..7
    const int sp  = r63 & 7;        // 0..7

    const int tid  = threadIdx.x;
    const int lane = tid & 63;
    const int wid  = tid >> 6;
    const int col  = lane & 31;
    const int half = lane >> 5;
    const int fblk0  = ftg * 256 + wid * 64;
    const int gstart = sp * GHALF;
    const size_t bq = (size_t)b * FF;

    // hoist y fragments for 2 f-subtiles (B operand), unpack hi/lo
    f16x8 qhf[FTG][4], qlf[FTG][4];
    #pragma unroll
    for (int fs = 0; fs < FTG; ++fs)
        #pragma unroll
        for (int ks = 0; ks < 4; ++ks) {
            const unsigned* yp =
                ypk + (bq + fblk0 + fs * 32 + col) * DPAD + ks * 16 + half * 8;
            unpack8(*(const uint4*)yp, *(const uint4*)(yp + 4),
                    qhf[fs][ks], qlf[fs][ks]);
        }

    if (tid < GHALF) wssh[tid] = wv[bq + gstart + tid];

    // staging: wave stages 4 KB contiguous LDS (conflict-free writes);
    // source chunk = slot ^ (row&15) picks xh/xl + offset (inverse swizzle).
    const int base = wid * 4096 + lane * 16;
    int rowj[4], soj[4];
    const unsigned short* sbj[4];
    #pragma unroll
    for (int j = 0; j < 4; ++j) {
        const int D = base + j * 1024;
        rowj[j] = D >> 8;
        const int c = ((D >> 4) & 15) ^ (rowj[j] & 15);
        sbj[j] = (c < 8) ? xh : xl;
        soj[j] = (c & 7) * 8;
    }

    uint4 st[4];
    #pragma unroll
    for (int j = 0; j < 4; ++j)
        st[j] = *(const uint4*)(sbj[j] + (bq + gstart + rowj[j]) * DPAD + soj[j]);

    float lsum[FTG], asum[FTG];
    #pragma unroll
    for (int fs = 0; fs < FTG; ++fs) { lsum[fs] = 0.f; asum[fs] = 0.f; }

    for (int t = 0; t < NSTEP; ++t) {
        const int buf = t & 1;
        #pragma unroll
        for (int j = 0; j < 4; ++j)
            *(uint4*)(&Kt[buf][base + j * 1024]) = st[j];
        if (t + 1 < NSTEP) {
            const int gn = gstart + (t + 1) * GSTEP;
            #pragma unroll
            for (int j = 0; j < 4; ++j)
                st[j] = *(const uint4*)(sbj[j] + (bq + gn + rowj[j]) * DPAD + soj[j]);
        }
        __syncthreads();

        #pragma unroll
        for (int gsub = 0; gsub < 2; ++gsub) {
            const int arow = gsub * 32 + col;
            const int rbase = arow << 8;
            const int ar15 = arow & 15;
            const float* wpb = wssh + t * GSTEP + gsub * 32 + 4 * half;
            #pragma unroll
            for (int fs = 0; fs < FTG; ++fs) {
                f32x16 acc;
                #pragma unroll
                for (int i = 0; i < 16; ++i) acc[i] = 0.f;
                #pragma unroll
                for (int ks = 0; ks < 4; ++ks) {
                    const int ch = ks * 2 + half;
                    f16x8 ahf = *(const f16x8*)(&Kt[buf][rbase + ((ch ^ ar15) << 4)]);
                    f16x8 alf = *(const f16x8*)(&Kt[buf][rbase + (((8 + ch) ^ ar15) << 4)]);
                    acc = __builtin_amdgcn_mfma_f32_32x32x16_f16(ahf, qlf[fs][ks], acc, 0, 0, 0);
                    acc = __builtin_amdgcn_mfma_f32_32x32x16_f16(alf, qhf[fs][ks], acc, 0, 0, 0);
                    acc = __builtin_amdgcn_mfma_f32_32x32x16_f16(ahf, qhf[fs][ks], acc, 0, 0, 0);
                }
                // D row g = (reg&3) + 8*(reg>>2) + 4*half
                #pragma unroll
                for (int q = 0; q < 4; ++q) {
                    float4 w4 = *(const float4*)(wpb + q * 8);
                    float p0 = __expf(acc[q * 4 + 0]);
                    float p1 = __expf(acc[q * 4 + 1]);
                    float p2 = __expf(acc[q * 4 + 2]);
                    float p3 = __expf(acc[q * 4 + 3]);
                    lsum[fs] += ((p0 + p1) + (p2 + p3));
                    asum[fs] = fmaf(p0, w4.x, fmaf(p1, w4.y,
                               fmaf(p2, w4.z, fmaf(p3, w4.w, asum[fs]))));
                }
            }
        }
    }

    #pragma unroll
    for (int fs = 0; fs < FTG; ++fs) {
        float l = lsum[fs] + __shfl_xor(lsum[fs], 32);
        float a = asum[fs] + __shfl_xor(asum[fs], 32);
        if (half == 0) {
            size_t o = ((size_t)sp * BB + b) * FF + fblk0 + fs * 32 + col;
            partL[o] = l;
            partA[o] = a;
        }
    }
}

// ---------------------------------------------------------------------------
// bn: combine split partials, BatchNorm over batch per channel f.
// ---------------------------------------------------------------------------
__global__ __launch_bounds__(256) void bn_kernel(
    const float* __restrict__ partL, const float* __restrict__ partA,
    const float* __restrict__ gamma, const float* __restrict__ beta,
    float* __restrict__ out)
{
    const int f = blockIdx.x * 256 + threadIdx.x;
    float v[BB];
    float mean = 0.f;
    #pragma unroll
    for (int b = 0; b < BB; ++b) {
        float l = 0.f, a = 0.f;
        #pragma unroll
        for (int s = 0; s < SPLIT; ++s) {
            l += partL[((size_t)s * BB + b) * FF + f];
            a += partA[((size_t)s * BB + b) * FF + f];
        }
        v[b] = a / l;
        mean += v[b];
    }
    mean *= (1.f / BB);
    float var = 0.f;
    #pragma unroll
    for (int b = 0; b < BB; ++b) {
        float d = v[b] - mean;
        var = fmaf(d, d, var);
    }
    var *= (1.f / BB);
    const float inv = rsqrtf(var + 1e-5f);
    const float g = gamma[f], be = beta[f];
    #pragma unroll
    for (int b = 0; b < BB; ++b)
        out[((size_t)b << 11) + f] = (v[b] - mean) * inv * g + be;
}

// ---------------------------------------------------------------------------
extern "C" void kernel_launch(void* const* d_in, const int* in_sizes, int n_in,
                              void* d_out, int out_size, void* d_ws, size_t ws_size,
                              hipStream_t stream)
{
    const float* x     = (const float*)d_in[0];
    const float* Wqkv  = (const float*)d_in[1];
    const float* Wout  = (const float*)d_in[2];
    // d_in[3] = b_out: cancels exactly under BatchNorm mean subtraction.
    const float* gamma = (const float*)d_in[4];
    const float* beta  = (const float*)d_in[5];

    char* wsb = (char*)d_ws;
    const size_t PANEL = (size_t)ROWS * DPAD * sizeof(unsigned short);  // 8 MB
    unsigned short* xh = (unsigned short*)(wsb);
    unsigned short* xl = (unsigned short*)(wsb + PANEL);
    unsigned*      ypk = (unsigned*)(wsb + 2 * PANEL);                  // 16 MB
    float*          wv = (float*)(wsb + 4 * PANEL);                     // 256 KB
    unsigned*     Mtpk = (unsigned*)(wsb + 4 * PANEL + 262144);         // 16 KB
    float*           u = (float*)(wsb + 4 * PANEL + 262144 + 16384);
    float*       partL = (float*)(wsb + 4 * PANEL + 262144 + 17408);
    float*       partA = partL + (size_t)SPLIT * BB * FF;
    // total ~= 37 MiB

    prep_kernel<<<dim3(17), dim3(256), 0, stream>>>(Wqkv, Wout, Mtpk, u);

    xymm_kernel<<<dim3(ROWS / 128), dim3(256), 0, stream>>>(
        x, Mtpk, u, xh, xl, ypk, wv);

    attn_kernel<<<dim3(BB * 8 * SPLIT), dim3(256), 0, stream>>>(
        xh, xl, ypk, wv, partL, partA);

    bn_kernel<<<dim3(FF / 256), dim3(256), 0, stream>>>(
        partL, partA, gamma, beta, (float*)d_out);
}

// Round 8
// 119.645 us; speedup vs baseline: 1.3826x; 1.1562x over previous
//
#include <hip/hip_runtime.h>
#include <math.h>

// Problem constants: B=32, F=2048, hw=49, A=1.
#define BB    32
#define FF    2048
#define HW    49
#define ROWS  (BB * FF)
#define DPAD  64
#define SPLIT 4
#define GSTEP 64
#define GHALF (FF / SPLIT)               // 512
#define NSTEP (GHALF / GSTEP)            // 8

typedef float f32x16 __attribute__((ext_vector_type(16)));
typedef _Float16 f16x8 __attribute__((ext_vector_type(8)));
typedef short s16x8 __attribute__((ext_vector_type(8)));

// exp2 via the amdgcn builtin -> single v_exp_f32, compiler-managed hazards.
__device__ inline float exp2_fast(float x) {
    return __builtin_amdgcn_exp2f(x);
}

// fp32 -> fp16 hi + fp16 lo (RNE), packed (hi<<16)|lo. Combined rel err ~2^-22.
__device__ inline unsigned f16pack(float v) {
    _Float16 h = (_Float16)v;
    _Float16 l = (_Float16)(v - (float)h);
    unsigned hb = (unsigned)__builtin_bit_cast(unsigned short, h);
    unsigned lb = (unsigned)__builtin_bit_cast(unsigned short, l);
    return (hb << 16) | lb;
}

__device__ inline void unpack8(uint4 a, uint4 b, f16x8& h, f16x8& l) {
    unsigned w[8] = {a.x, a.y, a.z, a.w, b.x, b.y, b.z, b.w};
    s16x8 hs, ls;
    #pragma unroll
    for (int i = 0; i < 8; ++i) {
        hs[i] = (short)(w[i] >> 16);
        ls[i] = (short)(w[i] & 0xFFFFu);
    }
    h = __builtin_bit_cast(f16x8, hs);
    l = __builtin_bit_cast(f16x8, ls);
}

// ---------------------------------------------------------------------------
// prep: M[j,d] = sum_e Wq[e,j] Wk[e,d] * log2(e)/7 -> Mtpk[d][j] (fp16 hi/lo)
//       u[d]   = sum_e Wv[e,d] * Wout[e]
// Scores come out in the log2 domain; softmax probs = exp2(s) = e^(q.k/7).
// ---------------------------------------------------------------------------
__global__ __launch_bounds__(256) void prep_kernel(
    const float* __restrict__ Wqkv, const float* __restrict__ Wout,
    unsigned* __restrict__ Mtpk, float* __restrict__ u)
{
    __shared__ float W2[98][52];
    const int tid = threadIdx.x;
    if (blockIdx.x < 16) {
        for (int i = tid; i < 98 * 52; i += 256) {
            int e = i / 52, j = i - e * 52;
            W2[e][j] = (j < HW) ? Wqkv[e * HW + j] : 0.f;
        }
        __syncthreads();
        const int d = blockIdx.x * 4 + (tid >> 6);
        const int j = tid & 63;
        float s = 0.f;
        if (d < HW && j < HW) {
            for (int e = 0; e < HW; ++e) s = fmaf(W2[e][j], W2[49 + e][d], s);
            s *= 0.2060992915555662f;      // log2(e) / 7
        }
        Mtpk[d * 64 + j] = f16pack(s);
    } else {
        if (tid < 64) {
            float s = 0.f;
            if (tid < HW)
                for (int e = 0; e < HW; ++e)
                    s = fmaf(Wqkv[(98 + e) * HW + tid], Wout[e], s);
            u[tid] = s;
        }
    }
}

// ---------------------------------------------------------------------------
// xymm: per 128 rows: coalesced x load via LDS bounce, fp16 hi/lo panels
// xh/xl, w = x.u, y = x.M (3-MFMA fp16 hi/lo) -> packed u32 panel ypk.
// dt processed sequentially (Mt frags reloaded) to keep VGPR pressure low.
// ---------------------------------------------------------------------------
__global__ __launch_bounds__(256) void xymm_kernel(
    const float* __restrict__ x, const unsigned* __restrict__ Mtpk,
    const float* __restrict__ u,
    unsigned short* __restrict__ xh, unsigned short* __restrict__ xl,
    unsigned* __restrict__ ypk, float* __restrict__ wv)
{
    __shared__ float xsh[128 * HW];
    __shared__ float ush[64];
    const int tid = threadIdx.x, lane = tid & 63, wid = tid >> 6;
    const int col = lane & 31, half = lane >> 5;
    if (tid < 64) ush[tid] = u[tid];

    {
        const float* xb = x + (size_t)blockIdx.x * 128 * HW;
        for (int i = tid; i < 128 * HW; i += 256) xsh[i] = xb[i];
    }
    __syncthreads();

    const int rloc = wid * 32 + col;
    const int row = blockIdx.x * 128 + rloc;

    f16x8 ah[4], al[4];
    float wp = 0.f;
    #pragma unroll
    for (int ks = 0; ks < 4; ++ks) {
        s16x8 hs, ls;
        #pragma unroll
        for (int i = 0; i < 8; ++i) {
            int d = ks * 16 + half * 8 + i;
            float t = (d < HW) ? xsh[rloc * HW + d] : 0.f;
            wp = fmaf(t, ush[d], wp);
            _Float16 h = (_Float16)t;
            _Float16 l = (_Float16)(t - (float)h);
            hs[i] = __builtin_bit_cast(short, h);
            ls[i] = __builtin_bit_cast(short, l);
        }
        ah[ks] = __builtin_bit_cast(f16x8, hs);
        al[ks] = __builtin_bit_cast(f16x8, ls);
        const size_t o = (size_t)row * DPAD + ks * 16 + half * 8;
        *(f16x8*)(xh + o) = ah[ks];
        *(f16x8*)(xl + o) = al[ks];
    }
    wp += __shfl_xor(wp, 32);
    if (half == 0) wv[row] = wp;

    const int r0 = blockIdx.x * 128 + wid * 32;
    for (int dt = 0; dt < 2; ++dt) {
        f16x8 mh[4], ml[4];
        #pragma unroll
        for (int ks = 0; ks < 4; ++ks) {
            const unsigned* mp = Mtpk + (dt * 32 + col) * 64 + ks * 16 + half * 8;
            unpack8(*(const uint4*)mp, *(const uint4*)(mp + 4), mh[ks], ml[ks]);
        }
        f32x16 acc;
        #pragma unroll
        for (int i = 0; i < 16; ++i) acc[i] = 0.f;
        #pragma unroll
        for (int ks = 0; ks < 4; ++ks) {
            acc = __builtin_amdgcn_mfma_f32_32x32x16_f16(ah[ks], ml[ks], acc, 0, 0, 0);
            acc = __builtin_amdgcn_mfma_f32_32x32x16_f16(al[ks], mh[ks], acc, 0, 0, 0);
            acc = __builtin_amdgcn_mfma_f32_32x32x16_f16(ah[ks], mh[ks], acc, 0, 0, 0);
        }
        #pragma unroll
        for (int reg = 0; reg < 16; ++reg) {
            int drow = (reg & 3) + 8 * (reg >> 2) + 4 * half;
            ypk[(size_t)(r0 + drow) * DPAD + dt * 32 + col] = f16pack(acc[reg]);
        }
    }
}

// ---------------------------------------------------------------------------
// attn: scores(log2-domain) = y . x^T (3-MFMA fp16 hi/lo), no-max softmax
// via v_exp_f32 builtin, scalar value w. Block: 4 waves x 32 f-cols each,
// GHALF=512 g-rows. K-tile 64 rows double-buffered, conflict-free swizzle.
// XCD sweeps its 4 b's sequentially -> ~2 MB live set, L2-resident.
// ---------------------------------------------------------------------------
__global__ __launch_bounds__(256, 3) void attn_kernel(
    const unsigned short* __restrict__ xh, const unsigned short* __restrict__ xl,
    const unsigned* __restrict__ ypk, const float* __restrict__ wv,
    float* __restrict__ partL, float* __restrict__ partA)
{
    __shared__ __align__(16) unsigned char Kt[2][GSTEP * 256];   // 2 x 16 KB
    __shared__ __align__(16) float wssh[GHALF];                  // 2 KB

    // XCD-chunked swizzle: 2048 blocks, 256 logical per XCD -> 4 b's/XCD.
    const int bid = blockIdx.x;
    const int L = (bid & 7) * 256 + (bid >> 3);
    const int b   = L >> 6;
    const int r63 = L & 63;
    const int ftg = r63 >> 2;       // 0..15
    const int sp  = r63 & 3;        // 0..3

    const int tid  = threadIdx.x;
    const int lane = tid & 63;
    const int wid  = tid >> 6;
    const int col  = lane & 31;
    const int half = lane >> 5;
    const int fblk0  = ftg * 128 + wid * 32;
    const int gstart = sp * GHALF;
    const size_t bq = (size_t)b * FF;

    // hoist y fragments (B operand, col = fblk0+col), unpack hi/lo
    f16x8 qhf[4], qlf[4];
    #pragma unroll
    for (int ks = 0; ks < 4; ++ks) {
        const unsigned* yp = ypk + (bq + fblk0 + col) * DPAD + ks * 16 + half * 8;
        unpack8(*(const uint4*)yp, *(const uint4*)(yp + 4), qhf[ks], qlf[ks]);
    }

    for (int i = tid; i < GHALF; i += 256) wssh[i] = wv[bq + gstart + i];

    // staging: wave stages 4 KB contiguous LDS (conflict-free writes);
    // source chunk = slot ^ (row&15) picks xh/xl + offset (inverse swizzle).
    const int base = wid * 4096 + lane * 16;
    int rowj[4], soj[4];
    const unsigned short* sbj[4];
    #pragma unroll
    for (int j = 0; j < 4; ++j) {
        const int D = base + j * 1024;
        rowj[j] = D >> 8;
        const int c = ((D >> 4) & 15) ^ (rowj[j] & 15);
        sbj[j] = (c < 8) ? xh : xl;
        soj[j] = (c & 7) * 8;
    }

    uint4 st[4];
    #pragma unroll
    for (int j = 0; j < 4; ++j)
        st[j] = *(const uint4*)(sbj[j] + (bq + gstart + rowj[j]) * DPAD + soj[j]);

    float lsum = 0.f, asum = 0.f;

    for (int t = 0; t < NSTEP; ++t) {
        const int buf = t & 1;
        #pragma unroll
        for (int j = 0; j < 4; ++j)
            *(uint4*)(&Kt[buf][base + j * 1024]) = st[j];
        if (t + 1 < NSTEP) {
            const int gn = gstart + (t + 1) * GSTEP;
            #pragma unroll
            for (int j = 0; j < 4; ++j)
                st[j] = *(const uint4*)(sbj[j] + (bq + gn + rowj[j]) * DPAD + soj[j]);
        }
        __syncthreads();

        #pragma unroll
        for (int gsub = 0; gsub < 2; ++gsub) {
            const int arow = gsub * 32 + col;
            const int rbase = arow << 8;
            const int ar15 = arow & 15;
            f32x16 acc;
            #pragma unroll
            for (int i = 0; i < 16; ++i) acc[i] = 0.f;
            #pragma unroll
            for (int ks = 0; ks < 4; ++ks) {
                const int ch = ks * 2 + half;
                f16x8 ahf = *(const f16x8*)(&Kt[buf][rbase + ((ch ^ ar15) << 4)]);
                f16x8 alf = *(const f16x8*)(&Kt[buf][rbase + (((8 + ch) ^ ar15) << 4)]);
                acc = __builtin_amdgcn_mfma_f32_32x32x16_f16(ahf, qlf[ks], acc, 0, 0, 0);
                acc = __builtin_amdgcn_mfma_f32_32x32x16_f16(alf, qhf[ks], acc, 0, 0, 0);
                acc = __builtin_amdgcn_mfma_f32_32x32x16_f16(ahf, qhf[ks], acc, 0, 0, 0);
            }
            // D row g = (reg&3) + 8*(reg>>2) + 4*half
            const float* wpb = wssh + t * GSTEP + gsub * 32 + 4 * half;
            #pragma unroll
            for (int q = 0; q < 4; ++q) {
                float4 w4 = *(const float4*)(wpb + q * 8);
                float p0 = exp2_fast(acc[q * 4 + 0]);
                float p1 = exp2_fast(acc[q * 4 + 1]);
                float p2 = exp2_fast(acc[q * 4 + 2]);
                float p3 = exp2_fast(acc[q * 4 + 3]);
                lsum += ((p0 + p1) + (p2 + p3));
                asum = fmaf(p0, w4.x, fmaf(p1, w4.y,
                       fmaf(p2, w4.z, fmaf(p3, w4.w, asum))));
            }
        }
    }

    lsum += __shfl_xor(lsum, 32);
    asum += __shfl_xor(asum, 32);
    if (half == 0) {
        size_t o = ((size_t)sp * BB + b) * FF + fblk0 + col;
        partL[o] = lsum;
        partA[o] = asum;
    }
}

// ---------------------------------------------------------------------------
// bn: combine split partials, BatchNorm over batch per channel f.
// Grid 32 x 64 threads: spread the 4 MB partial read over 32 CUs.
// ---------------------------------------------------------------------------
__global__ __launch_bounds__(64) void bn_kernel(
    const float* __restrict__ partL, const float* __restrict__ partA,
    const float* __restrict__ gamma, const float* __restrict__ beta,
    float* __restrict__ out)
{
    const int f = blockIdx.x * 64 + threadIdx.x;
    float v[BB];
    float mean = 0.f;
    #pragma unroll
    for (int b = 0; b < BB; ++b) {
        float l = 0.f, a = 0.f;
        #pragma unroll
        for (int s = 0; s < SPLIT; ++s) {
            l += partL[((size_t)s * BB + b) * FF + f];
            a += partA[((size_t)s * BB + b) * FF + f];
        }
        v[b] = a / l;
        mean += v[b];
    }
    mean *= (1.f / BB);
    float var = 0.f;
    #pragma unroll
    for (int b = 0; b < BB; ++b) {
        float d = v[b] - mean;
        var = fmaf(d, d, var);
    }
    var *= (1.f / BB);
    const float inv = rsqrtf(var + 1e-5f);
    const float g = gamma[f], be = beta[f];
    #pragma unroll
    for (int b = 0; b < BB; ++b)
        out[((size_t)b << 11) + f] = (v[b] - mean) * inv * g + be;
}

// ---------------------------------------------------------------------------
extern "C" void kernel_launch(void* const* d_in, const int* in_sizes, int n_in,
                              void* d_out, int out_size, void* d_ws, size_t ws_size,
                              hipStream_t stream)
{
    const float* x     = (const float*)d_in[0];
    const float* Wqkv  = (const float*)d_in[1];
    const float* Wout  = (const float*)d_in[2];
    // d_in[3] = b_out: cancels exactly under BatchNorm mean subtraction.
    const float* gamma = (const float*)d_in[4];
    const float* beta  = (const float*)d_in[5];

    char* wsb = (char*)d_ws;
    const size_t PANEL = (size_t)ROWS * DPAD * sizeof(unsigned short);  // 8 MB
    unsigned short* xh = (unsigned short*)(wsb);
    unsigned short* xl = (unsigned short*)(wsb + PANEL);
    unsigned*      ypk = (unsigned*)(wsb + 2 * PANEL);                  // 16 MB
    float*          wv = (float*)(wsb + 4 * PANEL);                     // 256 KB
    unsigned*     Mtpk = (unsigned*)(wsb + 4 * PANEL + 262144);         // 16 KB
    float*           u = (float*)(wsb + 4 * PANEL + 262144 + 16384);
    float*       partL = (float*)(wsb + 4 * PANEL + 262144 + 17408);
    float*       partA = partL + (size_t)SPLIT * BB * FF;
    // total ~= 35 MiB

    prep_kernel<<<dim3(17), dim3(256), 0, stream>>>(Wqkv, Wout, Mtpk, u);

    xymm_kernel<<<dim3(ROWS / 128), dim3(256), 0, stream>>>(
        x, Mtpk, u, xh, xl, ypk, wv);

    attn_kernel<<<dim3(BB * 16 * SPLIT), dim3(256), 0, stream>>>(
        xh, xl, ypk, wv, partL, partA);

    bn_kernel<<<dim3(FF / 64), dim3(64), 0, stream>>>(
        partL, partA, gamma, beta, (float*)d_out);
}